// Round 1
// baseline (13393.748 us; speedup 1.0000x reference)
//
#include <hip/hip_runtime.h>
#include <math.h>

#define B   64
#define T   1000
#define INP 64
#define HID 512
#define ACT 2

// ---------------------------------------------------------------------------
// K1: xproj[b,t,:] = inp[b,t,:] @ W_ih   -> written into the rnn_out slab of
// d_out (it is overwritten in-place by h during the recurrence).
// Block = 256 threads handles 16 rows x 512 cols; W_ih stays L2-resident.
// ---------------------------------------------------------------------------
__global__ __launch_bounds__(256) void xproj_kernel(
    const float* __restrict__ inp, const float* __restrict__ W_ih,
    float* __restrict__ rnn) {
  __shared__ float xin[16 * INP];          // 4 KB
  const int tid = threadIdx.x;
  const long r0 = (long)blockIdx.x * 16;   // first of 16 flat rows (b*T+t)

  // cooperative load: 16 rows x 64 floats = 256 float4
  const float4* inp4 = (const float4*)(inp + r0 * INP);
  ((float4*)xin)[tid] = inp4[tid];
  __syncthreads();

  const int j = tid, j2 = tid + 256;
  float acc0[16], acc1[16];
#pragma unroll
  for (int r = 0; r < 16; ++r) { acc0[r] = 0.f; acc1[r] = 0.f; }

  for (int i = 0; i < INP; ++i) {
    const float w0 = W_ih[i * HID + j];
    const float w1 = W_ih[i * HID + j2];
#pragma unroll
    for (int r = 0; r < 16; ++r) {
      const float x = xin[r * INP + i];    // LDS broadcast
      acc0[r] = fmaf(x, w0, acc0[r]);
      acc1[r] = fmaf(x, w1, acc1[r]);
    }
  }
#pragma unroll
  for (int r = 0; r < 16; ++r) {
    rnn[(r0 + r) * HID + j]  = acc0[r];
    rnn[(r0 + r) * HID + j2] = acc1[r];
  }
}

// ---------------------------------------------------------------------------
// K2: the sequential recurrence. One block per batch row (fully independent,
// no inter-block sync needed). 512 threads, 4-way k-split, float4 W_hh loads
// (each W element read exactly once per step per block; W_hh is L2-resident).
// xproj is read from the rnn slab and overwritten in place with h.
// ---------------------------------------------------------------------------
__global__ __launch_bounds__(512) void rnn_kernel(
    const float* __restrict__ hn, const float* __restrict__ W_hh,
    float* __restrict__ rnn, float* __restrict__ hn_out) {
  __shared__ float h[HID];                 // 2 KB
  __shared__ float part[4][HID];           // 8 KB

  const int tid = threadIdx.x;
  const int b   = blockIdx.x;
  h[tid] = hn[b * HID + tid];

  const int ks = tid >> 7;                 // k-slice 0..3 (128 k's each)
  const int jg = tid & 127;                // column group -> cols 4*jg..4*jg+3
  const float4* __restrict__ W4 = (const float4*)W_hh;  // [k*128 + j/4]
  float* __restrict__ rnn_b = rnn + (long)b * T * HID;
  __syncthreads();

  for (int t = 0; t < T; ++t) {
    // issue the xproj load early; it's independent of the k-loop
    const float xp = rnn_b[t * HID + tid];

    float4 acc = make_float4(0.f, 0.f, 0.f, 0.f);
    const int kbase = ks * 128;
#pragma unroll 8
    for (int kk = 0; kk < 128; ++kk) {
      const int k = kbase + kk;
      const float hk = h[k];               // LDS broadcast within k-slice
      const float4 w = W4[k * 128 + jg];   // coalesced, L2-resident
      acc.x = fmaf(hk, w.x, acc.x);
      acc.y = fmaf(hk, w.y, acc.y);
      acc.z = fmaf(hk, w.z, acc.z);
      acc.w = fmaf(hk, w.w, acc.w);
    }
    ((float4*)part[ks])[jg] = acc;
    __syncthreads();

    const float z = part[0][tid] + part[1][tid] + part[2][tid] + part[3][tid]
                  + xp;
    const float hv = 1.f / (1.f + __expf(-z));
    rnn_b[t * HID + tid] = hv;             // overwrite xproj with h (in place)
    h[tid] = hv;
    __syncthreads();                       // h/part ready before next step
  }

  hn_out[b * HID + tid] = h[tid];          // hn_last = h_{T-1}
}

// ---------------------------------------------------------------------------
// K3: out[b,t,:] = sigmoid(rnn[b,t,:] @ W_fc + b_fc). One wave per (b,t) row,
// shuffle reduction. Memory-bound on the 131 MB rnn read.
// ---------------------------------------------------------------------------
__global__ __launch_bounds__(256) void fc_kernel(
    const float* __restrict__ rnn, const float* __restrict__ W_fc,
    const float* __restrict__ b_fc, float* __restrict__ out) {
  const int lane = threadIdx.x & 63;
  const int wid  = threadIdx.x >> 6;
  const long row = (long)blockIdx.x * 4 + wid;     // flat (b*T+t), < 64000

  const float4* __restrict__ hrow = (const float4*)(rnn + row * HID);
  const float4* __restrict__ Wfc4 = (const float4*)W_fc;  // [512][2] flat

  float a0 = 0.f, a1 = 0.f;
#pragma unroll
  for (int u = 0; u < 2; ++u) {
    const float4 hv = hrow[lane * 2 + u];          // cols j0..j0+3
    const int j0 = lane * 8 + u * 4;
    const float4 wA = Wfc4[(j0 >> 1)];             // W[j0][0..1], W[j0+1][0..1]
    const float4 wB = Wfc4[(j0 >> 1) + 1];         // W[j0+2][0..1], W[j0+3][..]
    a0 += hv.x * wA.x + hv.y * wA.z + hv.z * wB.x + hv.w * wB.z;
    a1 += hv.x * wA.y + hv.y * wA.w + hv.z * wB.y + hv.w * wB.w;
  }
#pragma unroll
  for (int off = 32; off > 0; off >>= 1) {
    a0 += __shfl_down(a0, off, 64);
    a1 += __shfl_down(a1, off, 64);
  }
  if (lane == 0) {
    out[row * 2 + 0] = 1.f / (1.f + __expf(-(a0 + b_fc[0])));
    out[row * 2 + 1] = 1.f / (1.f + __expf(-(a1 + b_fc[1])));
  }
}

// ---------------------------------------------------------------------------
extern "C" void kernel_launch(void* const* d_in, const int* in_sizes, int n_in,
                              void* d_out, int out_size, void* d_ws,
                              size_t ws_size, hipStream_t stream) {
  const float* inp  = (const float*)d_in[0];  // [B,T,INP]
  const float* hn   = (const float*)d_in[1];  // [1,B,HID]
  const float* W_hh = (const float*)d_in[2];  // [HID,HID]
  const float* W_ih = (const float*)d_in[3];  // [INP,HID]
  const float* W_fc = (const float*)d_in[4];  // [HID,ACT]
  const float* b_fc = (const float*)d_in[5];  // [ACT]

  float* out    = (float*)d_out;              // [B,T,ACT]   (128000)
  float* hn_out = out + (long)B * T * ACT;    // [1,B,HID]   (32768)
  float* rnn    = hn_out + (long)B * HID;     // [B,T,HID]   (32768000)

  // K1: xproj into the rnn slab (overwritten in place by K2)
  hipLaunchKernelGGL(xproj_kernel, dim3((B * T) / 16), dim3(256), 0, stream,
                     inp, W_ih, rnn);
  // K2: the recurrence — 64 independent persistent blocks
  hipLaunchKernelGGL(rnn_kernel, dim3(B), dim3(512), 0, stream,
                     hn, W_hh, rnn, hn_out);
  // K3: FC head + sigmoid, plus hn_last already written by K2
  hipLaunchKernelGGL(fc_kernel, dim3((B * T) / 4), dim3(256), 0, stream,
                     rnn, W_fc, b_fc, out);
}